// Round 6
// baseline (131.862 us; speedup 1.0000x reference)
//
#include <hip/hip_runtime.h>
#include <stdint.h>

// Conv2d as implicit GEMM, bf16 MFMA.
// R6: 256x128 tile, BK=32, triple-buffered LDS, counted vmcnt(3) (never drains),
// 2 blocks/CU co-residency, 1 phase per K-tile.
// x: [32,128,56,56] f32, w: [256,128,3,3] f32 -> out: [32,256,56,56] f32
// GEMM: M=100352, N=256, K=1152 (k=(kh*3+kw)*128+ci). 36 K-tiles of 32. Grid 784.

#define CIN   128
#define HW_   56
#define CO_   256
#define KSZ   1152
#define IMGHW 3136
#define HP    58
#define NT    36
#define BUFB  24576        // per-buffer: A plane 16KB + B plane 8KB
#define XT_BYTES ((size_t)32 * HP * HP * CIN * 2)   // 27,557,888
#define WP_BYTES ((size_t)CO_ * KSZ * 2)            // 589,824
#define WS_NEED  (XT_BYTES + WP_BYTES)

typedef __attribute__((ext_vector_type(8))) __bf16 bf16x8;
typedef __attribute__((ext_vector_type(4))) float f32x4;
typedef __attribute__((ext_vector_type(8))) unsigned short ushort8;

__device__ __forceinline__ unsigned short f2bf(float f) {
    unsigned int u = __float_as_uint(f);
    u += 0x7fffu + ((u >> 16) & 1u);   // RNE
    return (unsigned short)(u >> 16);
}

__device__ __forceinline__ void gl2lds16(const void* g, void* l) {
    __builtin_amdgcn_global_load_lds(
        (const __attribute__((address_space(1))) void*)g,
        (__attribute__((address_space(3))) void*)l, 16, 0, 0);
}

// ---- weight pack: [co][ci][kh][kw] f32 -> [co][k] bf16, k=(kh*3+kw)*128+ci
__global__ void pack_weight(const float* __restrict__ w,
                            unsigned short* __restrict__ wp) {
    int idx = blockIdx.x * 256 + threadIdx.x;
    int co = idx / KSZ;
    int k  = idx - co * KSZ;
    int khkw = k >> 7;
    int ci = k & 127;
    wp[idx] = f2bf(w[(co * CIN + ci) * 9 + khkw]);
}

// ---- x transform: NCHW f32 -> padded NHWC bf16 [32][58][58][128]
__global__ __launch_bounds__(256)
void xform(const float* __restrict__ x, unsigned short* __restrict__ xt) {
    const int nb = blockIdx.x;
    const int n  = nb / HP;
    const int hp = nb - n * HP;
    unsigned short* orow = xt + ((size_t)n * HP + hp) * (HP * CIN);
    const int t = threadIdx.x;

    if (hp == 0 || hp == HP - 1) {
        for (int i = t; i < (HP * CIN) / 8; i += 256)
            ((ushort8*)orow)[i] = (ushort8){0, 0, 0, 0, 0, 0, 0, 0};
        return;
    }
    const int h = hp - 1;
    __shared__ unsigned short T[CIN][HP];
    const int wl = t & 63, cg = t >> 6;
    for (int c0 = 0; c0 < CIN; c0 += 4) {
        int ci = c0 + cg;
        if (wl < HW_)
            T[ci][wl] = f2bf(x[(((size_t)n * CIN + ci) * HW_ + h) * HW_ + wl]);
    }
    __syncthreads();
    const int ci = t & 127, wo = t >> 7;
    for (int wp_ = wo; wp_ < HP; wp_ += 2) {
        unsigned short v = 0;
        if (wp_ >= 1 && wp_ <= HW_) v = T[ci][wp_ - 1];
        orow[wp_ * CIN + ci] = v;
    }
}

// ---- main conv: 256x128 tile, BK=32, 8 waves (4m x 2n), wave 64x64, 3-buf
// LDS buf (24KB): A plane [128 row2][128B] @0, B plane [64 row2][128B] @16KB.
// Pairing: row2 = m>>1, logical chunk c = (m&1)*4 + kc (kc = 16B k-chunk 0..3),
// physical chunk c' = c ^ (row2&7).  2-way banks on frag reads (free).
__global__ __launch_bounds__(512, 4)
void conv8(const unsigned short* __restrict__ xt,
           const unsigned short* __restrict__ wpk,
           float* __restrict__ out)
{
    __shared__ __align__(16) char lds[3 * BUFB];   // 72 KiB -> 2 blocks/CU

    const int tid  = threadIdx.x;
    const int lane = tid & 63;
    const int wid  = tid >> 6;

    int bid = blockIdx.x;
    int flat = (bid & 7) * 98 + (bid >> 3);     // XCD swizzle, 784 = 8*98 bijective
    const int mt    = flat >> 1;
    const int ntile = flat & 1;
    const int m0 = mt << 8;

    // ---- staging thread-fixed source offsets ----
    // unit write: phys row2 = p*64 + (tid>>3), phys chunk = tid&7
    const int lc = (tid & 7) ^ ((tid >> 3) & 7);      // logical chunk
    uint32_t aoff[2];
    #pragma unroll
    for (int p = 0; p < 2; ++p) {
        int m = m0 + p * 128 + ((tid >> 3) << 1) + (lc >> 2);
        int n = m / IMGHW;
        int rem = m - n * IMGHW;
        int h = rem / HW_;
        int w = rem - h * HW_;
        aoff[p] = (uint32_t)((((n * HP + h) * HP + w) << 8) + ((lc & 3) << 4));
    }
    const int co_r = ntile * 128 + ((tid >> 3) << 1) + (lc >> 2);
    const uint32_t boff0 = (uint32_t)(co_r * (KSZ * 2) + ((lc & 3) << 4));

    // ---- fragment LDS offsets ----
    const int fr = lane & 15, fg = lane >> 4;
    const int cp = (((fr & 1) << 2) | fg) ^ ((fr >> 1) & 7);
    const int wm0 = (wid >> 1) << 6;            // 0,64,128,192
    const int wn0 = (wid & 1) << 6;             // 0,64
    const int aBase = ((wm0 >> 1) + (fr >> 1)) * 128 + cp * 16;
    const int bBase = 16384 + ((wn0 >> 1) + (fr >> 1)) * 128 + cp * 16;

    const char* xtc = (const char*)xt;
    const char* wpc = (const char*)wpk;

    f32x4 acc[4][4];
    #pragma unroll
    for (int i = 0; i < 4; ++i)
        #pragma unroll
        for (int j = 0; j < 4; ++j)
            acc[i][j] = (f32x4){0.f, 0.f, 0.f, 0.f};

    auto STAGE = [&](int t, int sb) {           // 3 loads/thread, wave-uniform count
        int tap = t >> 2;
        int kh = (tap * 11) >> 5;               // tap/3 for tap<9
        int kw = tap - kh * 3;
        uint32_t asrc = (uint32_t)(((kh * HP + kw) << 8) + ((t & 3) << 6));
        uint32_t bsrc = (uint32_t)(t << 6);
        char* B0 = &lds[sb * BUFB];
        gl2lds16(xtc + aoff[0] + asrc, B0 + tid * 16);
        gl2lds16(xtc + aoff[1] + asrc, B0 + 8192 + tid * 16);
        gl2lds16(wpc + boff0 + bsrc, B0 + 16384 + tid * 16);
    };

    #define LGKM0 do { asm volatile("s_waitcnt lgkmcnt(0)" ::: "memory"); \
                       __builtin_amdgcn_sched_barrier(0); } while (0)

    auto PHASE = [&](int t, int cb, int sb) {
        const char* L = &lds[cb * BUFB];
        ushort8 areg[4], breg[4];
        #pragma unroll
        for (int mf = 0; mf < 4; ++mf)
            areg[mf] = *(const ushort8*)(L + aBase + mf * 1024);
        #pragma unroll
        for (int nf = 0; nf < 4; ++nf)
            breg[nf] = *(const ushort8*)(L + bBase + nf * 1024);
        if (t + 2 < NT) STAGE(t + 2, sb);
        __builtin_amdgcn_s_barrier();
        LGKM0;
        __builtin_amdgcn_s_setprio(1);
        #pragma unroll
        for (int mf = 0; mf < 4; ++mf)
            #pragma unroll
            for (int nf = 0; nf < 4; ++nf)
                acc[mf][nf] = __builtin_amdgcn_mfma_f32_16x16x32_bf16(
                    __builtin_bit_cast(bf16x8, breg[nf]),
                    __builtin_bit_cast(bf16x8, areg[mf]),
                    acc[mf][nf], 0, 0, 0);
        __builtin_amdgcn_s_setprio(0);
        // counted gate: newest 3 loads (stage t+2) stay in flight; t+1 retired
        if (t + 2 < NT)      asm volatile("s_waitcnt vmcnt(3)" ::: "memory");
        else if (t + 1 < NT) asm volatile("s_waitcnt vmcnt(0)" ::: "memory");
        __builtin_amdgcn_s_barrier();
    };

    // ---- prologue: stage tiles 0,1; gate leaves tile1's loads in flight ----
    STAGE(0, 0);
    STAGE(1, 1);
    asm volatile("s_waitcnt vmcnt(3)" ::: "memory");
    __builtin_amdgcn_s_barrier();

    #pragma unroll 1
    for (int tt = 0; tt < NT; tt += 3) {        // NT=36, 12 iters, static buf ids
        PHASE(tt + 0, 0, 2);
        PHASE(tt + 1, 1, 0);
        PHASE(tt + 2, 2, 1);
    }

    // ---- epilogue: direct stores; D row=co, col=m; lanes 0-15 contiguous in w
    const int mwave = m0 + wm0;
    const int co0 = ntile * 128 + wn0 + (fg << 2);
    #pragma unroll
    for (int mf = 0; mf < 4; ++mf) {
        int m = mwave + mf * 16 + fr;
        int n = m / IMGHW;
        int hwr = m - n * IMGHW;
        uint32_t basem = (uint32_t)(n * (CO_ * IMGHW) + hwr);
        #pragma unroll
        for (int nf = 0; nf < 4; ++nf)
            #pragma unroll
            for (int q = 0; q < 4; ++q)
                out[basem + (uint32_t)(co0 + nf * 16 + q) * IMGHW] = acc[mf][nf][q];
    }
    #undef LGKM0
}

// ================= fallback (round-1 kernel, used if ws too small) ==========
#define BM    64
#define BK    32
#define NSTEP 36
#define LDSP  40

template<bool PACKED>
__global__ __launch_bounds__(256, 2)
void conv_fb(const float* __restrict__ x,
             const float* __restrict__ wraw,
             const unsigned short* __restrict__ wp,
             float* __restrict__ out)
{
    __shared__ __align__(16) unsigned short Al[2][BM][LDSP];
    __shared__ __align__(16) unsigned short Bl[2][CO_][LDSP];

    const int tid  = threadIdx.x;
    const int lane = tid & 63;
    const int wid  = tid >> 6;

    const int mb    = blockIdx.x;
    const int n_img = mb / 49;
    const int hw0   = (mb - n_img * 49) * BM;

    const int mm = lane;
    const int hw = hw0 + mm;
    const int h  = hw / HW_;
    const int w_ = hw - h * HW_;

    const int bco  = tid >> 2;
    const int bkkg = tid & 3;

    float   aPF[8];
    ushort8 bPF[4];

    auto loadA = [&](int step) {
        int khkw = step >> 2;
        int kh = khkw / 3, kw = khkw - (khkw / 3) * 3;
        int ci0 = (step & 3) * BK + wid * 8;
        int ih = h + kh - 1, iw = w_ + kw - 1;
        bool valid = ((unsigned)ih < (unsigned)HW_) && ((unsigned)iw < (unsigned)HW_);
        const float* px = x + (((size_t)(n_img * CIN + ci0) * HW_ + ih) * HW_ + iw);
        #pragma unroll
        for (int e = 0; e < 8; ++e)
            aPF[e] = valid ? px[e * IMGHW] : 0.f;
    };
    auto writeA = [&](int buf) {
        ushort8 v;
        #pragma unroll
        for (int e = 0; e < 8; ++e) v[e] = f2bf(aPF[e]);
        *(ushort8*)&Al[buf][mm][wid * 8] = v;
    };
    auto loadB = [&](int step) {
        if (PACKED) {
            int k0 = step * BK;
            #pragma unroll
            for (int r = 0; r < 4; ++r)
                bPF[r] = *(const ushort8*)&wp[(r * 64 + bco) * KSZ + k0 + bkkg * 8];
        } else {
            int khkw = step >> 2;
            int ci0 = (step & 3) * BK + bkkg * 8;
            #pragma unroll
            for (int r = 0; r < 4; ++r) {
                int co = r * 64 + bco;
                ushort8 v;
                #pragma unroll
                for (int e = 0; e < 8; ++e)
                    v[e] = f2bf(wraw[(co * CIN + ci0 + e) * 9 + khkw]);
                bPF[r] = v;
            }
        }
    };
    auto writeB = [&](int buf) {
        #pragma unroll
        for (int r = 0; r < 4; ++r)
            *(ushort8*)&Bl[buf][r * 64 + bco][bkkg * 8] = bPF[r];
    };

    f32x4 acc[4][4];
    #pragma unroll
    for (int i = 0; i < 4; ++i)
        #pragma unroll
        for (int j = 0; j < 4; ++j)
            acc[i][j] = (f32x4){0.f, 0.f, 0.f, 0.f};

    const int frow = lane & 15;
    const int fk   = (lane >> 4) * 8;

    loadA(0); loadB(0);
    writeA(0); writeB(0);
    __syncthreads();

    for (int s = 0; s < NSTEP; ++s) {
        const int cur = s & 1;
        if (s + 1 < NSTEP) { loadA(s + 1); loadB(s + 1); }

        ushort8 aF[4], bF[4];
        #pragma unroll
        for (int i = 0; i < 4; ++i)
            aF[i] = *(const ushort8*)&Bl[cur][wid * 64 + i * 16 + frow][fk];
        #pragma unroll
        for (int j = 0; j < 4; ++j)
            bF[j] = *(const ushort8*)&Al[cur][j * 16 + frow][fk];

        #pragma unroll
        for (int i = 0; i < 4; ++i)
            #pragma unroll
            for (int j = 0; j < 4; ++j)
                acc[i][j] = __builtin_amdgcn_mfma_f32_16x16x32_bf16(
                    __builtin_bit_cast(bf16x8, aF[i]),
                    __builtin_bit_cast(bf16x8, bF[j]),
                    acc[i][j], 0, 0, 0);

        if (s + 1 < NSTEP) { writeA(cur ^ 1); writeB(cur ^ 1); }
        __syncthreads();
    }

    float* ob = out + (size_t)n_img * (CO_ * IMGHW) + hw0;
    #pragma unroll
    for (int i = 0; i < 4; ++i) {
        int co0 = wid * 64 + i * 16 + (lane >> 4) * 4;
        #pragma unroll
        for (int j = 0; j < 4; ++j) {
            int mcol = j * 16 + (lane & 15);
            #pragma unroll
            for (int q = 0; q < 4; ++q)
                ob[(size_t)(co0 + q) * IMGHW + mcol] = acc[i][j][q];
        }
    }
}

extern "C" void kernel_launch(void* const* d_in, const int* in_sizes, int n_in,
                              void* d_out, int out_size, void* d_ws, size_t ws_size,
                              hipStream_t stream) {
    (void)in_sizes; (void)n_in; (void)out_size;
    const float* x  = (const float*)d_in[0];
    const float* wt = (const float*)d_in[1];
    float* out = (float*)d_out;

    if (ws_size >= WS_NEED) {
        unsigned short* xt  = (unsigned short*)d_ws;
        unsigned short* wpk = (unsigned short*)((char*)d_ws + XT_BYTES);
        xform<<<32 * HP, 256, 0, stream>>>(x, xt);
        pack_weight<<<(CO_ * KSZ) / 256, 256, 0, stream>>>(wt, wpk);
        conv8<<<784, 512, 0, stream>>>(xt, wpk, out);
    } else if (ws_size >= WP_BYTES) {
        unsigned short* wpk = (unsigned short*)d_ws;
        pack_weight<<<(CO_ * KSZ) / 256, 256, 0, stream>>>(wt, wpk);
        conv_fb<true><<<100352 / BM, 256, 0, stream>>>(x, wt, wpk, out);
    } else {
        conv_fb<false><<<100352 / BM, 256, 0, stream>>>(x, wt, nullptr, out);
    }
}

// Round 7
// 100.461 us; speedup vs baseline: 1.3126x; 1.3126x over previous
//
#include <hip/hip_runtime.h>
#include <stdint.h>

// Conv2d as implicit GEMM, bf16 MFMA.
// R7: 256x256 tile, BK=64, 2 phases/K-tile, compiler-managed lgkm waits,
// counted vmcnt(4) pre-barrier gates (never drains in steady state).
// x: [32,128,56,56] f32, w: [256,128,3,3] f32 -> out: [32,256,56,56] f32
// GEMM: M=100352, N=256, K=1152 (k=(kh*3+kw)*128+ci). 18 K-tiles of 64. Grid 392.

#define CIN   128
#define HW_   56
#define CO_   256
#define KSZ   1152
#define IMGHW 3136
#define HP    58
#define NT    18
#define BUFSZ 65536        // 4 planes x 16KB: A_kh0 A_kh1 B_kh0 B_kh1
#define XT_BYTES ((size_t)32 * HP * HP * CIN * 2)   // 27,557,888
#define WP_BYTES ((size_t)CO_ * KSZ * 2)            // 589,824
#define WS_NEED  (XT_BYTES + WP_BYTES)

typedef __attribute__((ext_vector_type(8))) __bf16 bf16x8;
typedef __attribute__((ext_vector_type(4))) float f32x4;
typedef __attribute__((ext_vector_type(8))) unsigned short ushort8;

__device__ __forceinline__ unsigned short f2bf(float f) {
    unsigned int u = __float_as_uint(f);
    u += 0x7fffu + ((u >> 16) & 1u);   // RNE
    return (unsigned short)(u >> 16);
}

__device__ __forceinline__ void gl2lds16(const void* g, void* l) {
    __builtin_amdgcn_global_load_lds(
        (const __attribute__((address_space(1))) void*)g,
        (__attribute__((address_space(3))) void*)l, 16, 0, 0);
}

// ---- weight pack: [co][ci][kh][kw] f32 -> [co][k] bf16, k=(kh*3+kw)*128+ci
__global__ void pack_weight(const float* __restrict__ w,
                            unsigned short* __restrict__ wp) {
    int idx = blockIdx.x * 256 + threadIdx.x;
    int co = idx / KSZ;
    int k  = idx - co * KSZ;
    int khkw = k >> 7;
    int ci = k & 127;
    wp[idx] = f2bf(w[(co * CIN + ci) * 9 + khkw]);
}

// ---- x transform: NCHW f32 -> padded NHWC bf16 [32][58][58][128]
__global__ __launch_bounds__(256)
void xform(const float* __restrict__ x, unsigned short* __restrict__ xt) {
    const int nb = blockIdx.x;
    const int n  = nb / HP;
    const int hp = nb - n * HP;
    unsigned short* orow = xt + ((size_t)n * HP + hp) * (HP * CIN);
    const int t = threadIdx.x;

    if (hp == 0 || hp == HP - 1) {
        for (int i = t; i < (HP * CIN) / 8; i += 256)
            ((ushort8*)orow)[i] = (ushort8){0, 0, 0, 0, 0, 0, 0, 0};
        return;
    }
    const int h = hp - 1;
    __shared__ unsigned short T[CIN][HP];
    const int wl = t & 63, cg = t >> 6;
    for (int c0 = 0; c0 < CIN; c0 += 4) {
        int ci = c0 + cg;
        if (wl < HW_)
            T[ci][wl] = f2bf(x[(((size_t)n * CIN + ci) * HW_ + h) * HW_ + wl]);
    }
    __syncthreads();
    const int ci = t & 127, wo = t >> 7;
    for (int wp_ = wo; wp_ < HP; wp_ += 2) {
        unsigned short v = 0;
        if (wp_ >= 1 && wp_ <= HW_) v = T[ci][wp_ - 1];
        orow[wp_ * CIN + ci] = v;
    }
}

// ---- main conv: 256x256 tile, BK=64, 8 waves (2m x 4n), wave 128x64
__global__ __launch_bounds__(512, 2)
void conv2p(const unsigned short* __restrict__ xt,
            const unsigned short* __restrict__ wpk,
            float* __restrict__ out)
{
    __shared__ __align__(16) char lds[2 * BUFSZ];   // 128 KiB, 1 block/CU

    const int tid  = threadIdx.x;
    const int lane = tid & 63;
    const int wid  = tid >> 6;

    int bid = blockIdx.x;
    bid = (bid & 7) * 49 + (bid >> 3);          // XCD swizzle, 392 = 8*49 bijective
    const int m0 = bid << 8;

    // ---- staging: thread writes phys (row = tid>>2 + p*128, chunk = tid&3)
    // logical chunk = phys ^ s(row), s(row) = (row&3)^((row>>2)&3)
    const int lc = (tid & 3) ^ ((tid >> 2) & 3) ^ ((tid >> 4) & 3);
    uint32_t aoff[2], boff[2];
    #pragma unroll
    for (int p = 0; p < 2; ++p) {
        int m = m0 + (tid >> 2) + p * 128;      // per-row: handles image crossing
        int n = m / IMGHW;
        int rem = m - n * IMGHW;
        int h = rem / HW_;
        int w = rem - h * HW_;
        aoff[p] = (uint32_t)((((n * HP + h) * HP + w) << 8) + (lc << 4));
        boff[p] = (uint32_t)(((tid >> 2) + p * 128) * (KSZ * 2) + (lc << 4));
    }

    // ---- fragment LDS offsets (swizzled reads; same s(row), row&15 == fr) ----
    const int fr = lane & 15, fg = lane >> 4;
    const int sw = (fr & 3) ^ ((fr >> 2) & 3);
    const int cswz = (fg ^ sw) << 4;
    const int wm0 = (wid >> 2) << 7;            // 0 / 128
    const int wn0 = (wid & 3) << 6;             // 0..192
    const int aRB = (wm0 + fr) * 64 + cswz;             // + mf*1024 + kh*16384 + bufo
    const int bRB = 32768 + (wn0 + fr) * 64 + cswz;     // + nf*1024 + kh*16384 + bufo

    const char* xtc = (const char*)xt;
    const char* wpc = (const char*)wpk;

    f32x4 acc[8][4];
    #pragma unroll
    for (int i = 0; i < 8; ++i)
        #pragma unroll
        for (int j = 0; j < 4; ++j)
            acc[i][j] = (f32x4){0.f, 0.f, 0.f, 0.f};

    // stage k-half kh of K-tile t into buf t&1: exactly 4 loads/thread
    auto STAGE = [&](int t, int kh) {
        const int bufo = (t & 1) * BUFSZ;
        int tap = t >> 1;
        int khr = (tap * 11) >> 5;              // tap/3 for tap<9
        int kwr = tap - khr * 3;
        uint32_t asl = (uint32_t)(((khr * HP + kwr) << 8) + ((t & 1) << 7) + (kh << 6));
        uint32_t bsl = (uint32_t)((t << 7) + (kh << 6));
        char* DA = &lds[bufo + kh * 16384];
        char* DB = &lds[bufo + 32768 + kh * 16384];
        gl2lds16(xtc + aoff[0] + asl, DA + tid * 16);
        gl2lds16(xtc + aoff[1] + asl, DA + 8192 + tid * 16);
        gl2lds16(wpc + boff[0] + bsl, DB + tid * 16);
        gl2lds16(wpc + boff[1] + bsl, DB + 8192 + tid * 16);
    };

    // one phase: 12 ds_reads, prefetch-stage, counted gate, barrier, 32 MFMA.
    // lgkm waits are COMPILER-MANAGED (fine-grained, interleaved into MFMAs).
    auto PHASE = [&](int t, int kh) {
        const char* L = lds + (t & 1) * BUFSZ + kh * 16384;
        ushort8 breg[4], areg[8];
        #pragma unroll
        for (int nf = 0; nf < 4; ++nf)
            breg[nf] = *(const ushort8*)(L + bRB + nf * 1024);
        #pragma unroll
        for (int mf = 0; mf < 8; ++mf)
            areg[mf] = *(const ushort8*)(L + aRB + mf * 1024);

        // prefetch: A(t): stage(t+1,kh0); B(t): stage(t+1,kh1)
        if (t + 1 < NT) STAGE(t + 1, kh);

        // counted gate BEFORE barrier (cross-wave visibility: gate->barrier->read)
        if (t + 1 < NT)      asm volatile("s_waitcnt vmcnt(4)" ::: "memory");
        else if (kh == 0)    asm volatile("s_waitcnt vmcnt(0)" ::: "memory");
        __builtin_amdgcn_sched_barrier(0);      // pin reads+stages above barrier
        __builtin_amdgcn_s_barrier();

        __builtin_amdgcn_s_setprio(1);
        #pragma unroll
        for (int mf = 0; mf < 8; ++mf)
            #pragma unroll
            for (int nf = 0; nf < 4; ++nf)
                acc[mf][nf] = __builtin_amdgcn_mfma_f32_16x16x32_bf16(
                    __builtin_bit_cast(bf16x8, breg[nf]),
                    __builtin_bit_cast(bf16x8, areg[mf]),
                    acc[mf][nf], 0, 0, 0);
        __builtin_amdgcn_s_setprio(0);
    };

    // ---- prologue: tile0 both k-halves; gate kh0 landed, leave kh1 in flight
    STAGE(0, 0); STAGE(0, 1);
    asm volatile("s_waitcnt vmcnt(4)" ::: "memory");
    __builtin_amdgcn_s_barrier();

    #pragma unroll 1
    for (int t = 0; t < NT; ++t) {
        PHASE(t, 0);
        PHASE(t, 1);
    }

    // ---- epilogue: direct stores; D row=co, col=m; lanes 0-15 contiguous in w
    const int mwave = m0 + wm0;
    const int co0 = wn0 + (fg << 2);
    #pragma unroll
    for (int mf = 0; mf < 8; ++mf) {
        int m = mwave + mf * 16 + fr;
        int n = m / IMGHW;
        int hwr = m - n * IMGHW;
        uint32_t basem = (uint32_t)(n * (CO_ * IMGHW) + hwr);
        #pragma unroll
        for (int nf = 0; nf < 4; ++nf)
            #pragma unroll
            for (int q = 0; q < 4; ++q)
                out[basem + (uint32_t)(co0 + nf * 16 + q) * IMGHW] = acc[mf][nf][q];
    }
}

// ================= fallback (round-1 kernel, used if ws too small) ==========
#define BM    64
#define BK    32
#define NSTEP 36
#define LDSP  40

template<bool PACKED>
__global__ __launch_bounds__(256, 2)
void conv_fb(const float* __restrict__ x,
             const float* __restrict__ wraw,
             const unsigned short* __restrict__ wp,
             float* __restrict__ out)
{
    __shared__ __align__(16) unsigned short Al[2][BM][LDSP];
    __shared__ __align__(16) unsigned short Bl[2][CO_][LDSP];

    const int tid  = threadIdx.x;
    const int lane = tid & 63;
    const int wid  = tid >> 6;

    const int mb    = blockIdx.x;
    const int n_img = mb / 49;
    const int hw0   = (mb - n_img * 49) * BM;

    const int mm = lane;
    const int hw = hw0 + mm;
    const int h  = hw / HW_;
    const int w_ = hw - h * HW_;

    const int bco  = tid >> 2;
    const int bkkg = tid & 3;

    float   aPF[8];
    ushort8 bPF[4];

    auto loadA = [&](int step) {
        int khkw = step >> 2;
        int kh = khkw / 3, kw = khkw - (khkw / 3) * 3;
        int ci0 = (step & 3) * BK + wid * 8;
        int ih = h + kh - 1, iw = w_ + kw - 1;
        bool valid = ((unsigned)ih < (unsigned)HW_) && ((unsigned)iw < (unsigned)HW_);
        const float* px = x + (((size_t)(n_img * CIN + ci0) * HW_ + ih) * HW_ + iw);
        #pragma unroll
        for (int e = 0; e < 8; ++e)
            aPF[e] = valid ? px[e * IMGHW] : 0.f;
    };
    auto writeA = [&](int buf) {
        ushort8 v;
        #pragma unroll
        for (int e = 0; e < 8; ++e) v[e] = f2bf(aPF[e]);
        *(ushort8*)&Al[buf][mm][wid * 8] = v;
    };
    auto loadB = [&](int step) {
        if (PACKED) {
            int k0 = step * BK;
            #pragma unroll
            for (int r = 0; r < 4; ++r)
                bPF[r] = *(const ushort8*)&wp[(r * 64 + bco) * KSZ + k0 + bkkg * 8];
        } else {
            int khkw = step >> 2;
            int ci0 = (step & 3) * BK + bkkg * 8;
            #pragma unroll
            for (int r = 0; r < 4; ++r) {
                int co = r * 64 + bco;
                ushort8 v;
                #pragma unroll
                for (int e = 0; e < 8; ++e)
                    v[e] = f2bf(wraw[(co * CIN + ci0 + e) * 9 + khkw]);
                bPF[r] = v;
            }
        }
    };
    auto writeB = [&](int buf) {
        #pragma unroll
        for (int r = 0; r < 4; ++r)
            *(ushort8*)&Bl[buf][r * 64 + bco][bkkg * 8] = bPF[r];
    };

    f32x4 acc[4][4];
    #pragma unroll
    for (int i = 0; i < 4; ++i)
        #pragma unroll
        for (int j = 0; j < 4; ++j)
            acc[i][j] = (f32x4){0.f, 0.f, 0.f, 0.f};

    const int frow = lane & 15;
    const int fk   = (lane >> 4) * 8;

    loadA(0); loadB(0);
    writeA(0); writeB(0);
    __syncthreads();

    for (int s = 0; s < NSTEP; ++s) {
        const int cur = s & 1;
        if (s + 1 < NSTEP) { loadA(s + 1); loadB(s + 1); }

        ushort8 aF[4], bF[4];
        #pragma unroll
        for (int i = 0; i < 4; ++i)
            aF[i] = *(const ushort8*)&Bl[cur][wid * 64 + i * 16 + frow][fk];
        #pragma unroll
        for (int j = 0; j < 4; ++j)
            bF[j] = *(const ushort8*)&Al[cur][j * 16 + frow][fk];

        #pragma unroll
        for (int i = 0; i < 4; ++i)
            #pragma unroll
            for (int j = 0; j < 4; ++j)
                acc[i][j] = __builtin_amdgcn_mfma_f32_16x16x32_bf16(
                    __builtin_bit_cast(bf16x8, aF[i]),
                    __builtin_bit_cast(bf16x8, bF[j]),
                    acc[i][j], 0, 0, 0);

        if (s + 1 < NSTEP) { writeA(cur ^ 1); writeB(cur ^ 1); }
        __syncthreads();
    }

    float* ob = out + (size_t)n_img * (CO_ * IMGHW) + hw0;
    #pragma unroll
    for (int i = 0; i < 4; ++i) {
        int co0 = wid * 64 + i * 16 + (lane >> 4) * 4;
        #pragma unroll
        for (int j = 0; j < 4; ++j) {
            int mcol = j * 16 + (lane & 15);
            #pragma unroll
            for (int q = 0; q < 4; ++q)
                ob[(size_t)(co0 + q) * IMGHW + mcol] = acc[i][j][q];
        }
    }
}

extern "C" void kernel_launch(void* const* d_in, const int* in_sizes, int n_in,
                              void* d_out, int out_size, void* d_ws, size_t ws_size,
                              hipStream_t stream) {
    (void)in_sizes; (void)n_in; (void)out_size;
    const float* x  = (const float*)d_in[0];
    const float* wt = (const float*)d_in[1];
    float* out = (float*)d_out;

    if (ws_size >= WS_NEED) {
        unsigned short* xt  = (unsigned short*)d_ws;
        unsigned short* wpk = (unsigned short*)((char*)d_ws + XT_BYTES);
        xform<<<32 * HP, 256, 0, stream>>>(x, xt);
        pack_weight<<<(CO_ * KSZ) / 256, 256, 0, stream>>>(wt, wpk);
        conv2p<<<392, 512, 0, stream>>>(xt, wpk, out);
    } else if (ws_size >= WP_BYTES) {
        unsigned short* wpk = (unsigned short*)d_ws;
        pack_weight<<<(CO_ * KSZ) / 256, 256, 0, stream>>>(wt, wpk);
        conv_fb<true><<<100352 / BM, 256, 0, stream>>>(x, wt, wpk, out);
    } else {
        conv_fb<false><<<100352 / BM, 256, 0, stream>>>(x, wt, nullptr, out);
    }
}

// Round 8
// 99.968 us; speedup vs baseline: 1.3190x; 1.0049x over previous
//
#include <hip/hip_runtime.h>
#include <stdint.h>

// Conv2d as implicit GEMM, bf16 MFMA.
// R8: 256x256 tile, BK=64, 2 phases/K-tile, REGISTER double-buffering:
// each phase ds_reads the NEXT phase's fragments, then MFMAs the current ones
// (no same-phase read->MFMA dependence), counted vmcnt(4), R6's verified
// zero-conflict paired-row LDS layout.
// GEMM: M=100352, N=256, K=1152 (k=(kh*3+kw)*128+ci). 18 K-tiles. Grid 392.

#define CIN   128
#define HW_   56
#define CO_   256
#define KSZ   1152
#define IMGHW 3136
#define HP    58
#define NT    18
#define BUFSZ 65536        // A:[kh0@0,kh1@16K]  B:[kh0@32K,kh1@48K], 16KB planes
#define XT_BYTES ((size_t)32 * HP * HP * CIN * 2)   // 27,557,888
#define WP_BYTES ((size_t)CO_ * KSZ * 2)            // 589,824
#define WS_NEED  (XT_BYTES + WP_BYTES)

typedef __attribute__((ext_vector_type(8))) __bf16 bf16x8;
typedef __attribute__((ext_vector_type(4))) float f32x4;
typedef __attribute__((ext_vector_type(8))) unsigned short ushort8;

__device__ __forceinline__ unsigned short f2bf(float f) {
    unsigned int u = __float_as_uint(f);
    u += 0x7fffu + ((u >> 16) & 1u);   // RNE
    return (unsigned short)(u >> 16);
}

__device__ __forceinline__ void gl2lds16(const void* g, void* l) {
    __builtin_amdgcn_global_load_lds(
        (const __attribute__((address_space(1))) void*)g,
        (__attribute__((address_space(3))) void*)l, 16, 0, 0);
}

// ---- weight pack: [co][ci][kh][kw] f32 -> [co][k] bf16, k=(kh*3+kw)*128+ci
__global__ void pack_weight(const float* __restrict__ w,
                            unsigned short* __restrict__ wp) {
    int idx = blockIdx.x * 256 + threadIdx.x;
    int co = idx / KSZ;
    int k  = idx - co * KSZ;
    int khkw = k >> 7;
    int ci = k & 127;
    wp[idx] = f2bf(w[(co * CIN + ci) * 9 + khkw]);
}

// ---- x transform: NCHW f32 -> padded NHWC bf16 [32][58][58][128]
__global__ __launch_bounds__(256)
void xform(const float* __restrict__ x, unsigned short* __restrict__ xt) {
    const int nb = blockIdx.x;
    const int n  = nb / HP;
    const int hp = nb - n * HP;
    unsigned short* orow = xt + ((size_t)n * HP + hp) * (HP * CIN);
    const int t = threadIdx.x;

    if (hp == 0 || hp == HP - 1) {
        for (int i = t; i < (HP * CIN) / 8; i += 256)
            ((ushort8*)orow)[i] = (ushort8){0, 0, 0, 0, 0, 0, 0, 0};
        return;
    }
    const int h = hp - 1;
    __shared__ unsigned short T[CIN][HP];
    const int wl = t & 63, cg = t >> 6;
    for (int c0 = 0; c0 < CIN; c0 += 4) {
        int ci = c0 + cg;
        if (wl < HW_)
            T[ci][wl] = f2bf(x[(((size_t)n * CIN + ci) * HW_ + h) * HW_ + wl]);
    }
    __syncthreads();
    const int ci = t & 127, wo = t >> 7;
    for (int wp_ = wo; wp_ < HP; wp_ += 2) {
        unsigned short v = 0;
        if (wp_ >= 1 && wp_ <= HW_) v = T[ci][wp_ - 1];
        orow[wp_ * CIN + ci] = v;
    }
}

// ---- main conv: 256x256 tile, BK=64, 8 waves (2m x 4n), wave 128x64
__global__ __launch_bounds__(512, 2)
void convrd(const unsigned short* __restrict__ xt,
            const unsigned short* __restrict__ wpk,
            float* __restrict__ out)
{
    __shared__ __align__(16) char lds[2 * BUFSZ];   // 128 KiB, 1 block/CU

    const int tid  = threadIdx.x;
    const int lane = tid & 63;
    const int wid  = tid >> 6;

    int bid = blockIdx.x;
    bid = (bid & 7) * 49 + (bid >> 3);          // XCD swizzle, 392 = 8*49 bijective
    const int m0 = bid << 8;

    // ---- staging (R6-verified paired-row layout, zero bank conflicts) ----
    // dest: plane + p*8192 + tid*16  ->  row2 = p*64 + (tid>>3), phys chunk tid&7
    // stored(row2,cp): m-row = 2*row2 + ((cp^row2)>>2&1... via lc), kc=(cp&3)^(row2&3)
    const int lc = (tid & 7) ^ ((tid >> 3) & 7);
    uint32_t aoff[2], boff[2];
    #pragma unroll
    for (int p = 0; p < 2; ++p) {
        int r = p * 128 + ((tid >> 3) << 1) + (lc >> 2);
        int m = m0 + r;
        int n = m / IMGHW;
        int rem = m - n * IMGHW;
        int h = rem / HW_;
        int w = rem - h * HW_;
        aoff[p] = (uint32_t)((((n * HP + h) * HP + w) << 8) + ((lc & 3) << 4));
        boff[p] = (uint32_t)(r * (KSZ * 2) + ((lc & 3) << 4));
    }

    // ---- fragment LDS offsets (R6-verified) ----
    const int fr = lane & 15, fg = lane >> 4;
    const int cp = (((fr & 1) << 2) | fg) ^ ((fr >> 1) & 7);
    const int wm0 = (wid >> 2) << 7;            // 0 / 128
    const int wn0 = (wid & 3) << 6;             // 0..192
    const int aRB = (((wm0 >> 1) + (fr >> 1)) << 7) + (cp << 4);  // + mf*1024
    const int bRB = (((wn0 >> 1) + (fr >> 1)) << 7) + (cp << 4);  // + nf*1024

    const char* xtc = (const char*)xt;
    const char* wpc = (const char*)wpk;

    f32x4 acc[8][4];
    #pragma unroll
    for (int i = 0; i < 8; ++i)
        #pragma unroll
        for (int j = 0; j < 4; ++j)
            acc[i][j] = (f32x4){0.f, 0.f, 0.f, 0.f};

    ushort8 a0[8], b0[4];   // fragments for even phases (kh0 data)
    ushort8 a1[8], b1[4];   // fragments for odd phases (kh1 data)

    auto STAGE = [&](int t, int kh) {           // 4 loads/thread, wave-uniform
        const int bufo = (t & 1) * BUFSZ;
        int tap = t >> 1;
        int khr = (tap * 11) >> 5;              // tap/3 for tap<9
        int kwr = tap - khr * 3;
        uint32_t asl = (uint32_t)(((khr * HP + kwr) << 8) + ((t & 1) << 7) + (kh << 6));
        uint32_t bsl = (uint32_t)((t << 7) + (kh << 6));
        char* DA = &lds[bufo + kh * 16384];
        char* DB = &lds[bufo + 32768 + kh * 16384];
        gl2lds16(xtc + aoff[0] + asl, DA + tid * 16);
        gl2lds16(xtc + aoff[1] + asl, DA + 8192 + tid * 16);
        gl2lds16(wpc + boff[0] + bsl, DB + tid * 16);
        gl2lds16(wpc + boff[1] + bsl, DB + 8192 + tid * 16);
    };

    #define LOADF(A_, B_, Apl, Bpl) do { \
        _Pragma("unroll") for (int i_ = 0; i_ < 4; ++i_) \
            B_[i_] = *(const ushort8*)((Bpl) + bRB + i_ * 1024); \
        _Pragma("unroll") for (int i_ = 0; i_ < 8; ++i_) \
            A_[i_] = *(const ushort8*)((Apl) + aRB + i_ * 1024); \
    } while (0)

    #define MMALL(A_, B_) do { \
        _Pragma("unroll") for (int mf_ = 0; mf_ < 8; ++mf_) \
            _Pragma("unroll") for (int nf_ = 0; nf_ < 4; ++nf_) \
                acc[mf_][nf_] = __builtin_amdgcn_mfma_f32_16x16x32_bf16( \
                    __builtin_bit_cast(bf16x8, B_[nf_]), \
                    __builtin_bit_cast(bf16x8, A_[mf_]), \
                    acc[mf_][nf_], 0, 0, 0); \
    } while (0)

    // ---- prologue: stage (0,kh0),(0,kh1),(1,kh0); gate so tile0 fully landed,
    // leave (1,kh0)'s 4 loads in flight; preload phase-0 fragments.
    STAGE(0, 0); STAGE(0, 1); STAGE(1, 0);
    asm volatile("s_waitcnt vmcnt(4)" ::: "memory");
    __builtin_amdgcn_s_barrier();
    LOADF(a0, b0, lds + 0, lds + 32768);        // (0,kh0)

    #pragma unroll 1
    for (int t = 0; t < NT; ++t) {
        const int bufo = (t & 1) * BUFSZ;
        const char* L  = lds + bufo;            // current tile's buffer
        const char* Ln = lds + (bufo ^ BUFSZ);  // next tile's buffer

        // ===== P0: load (t,kh1) frags; stage (t+1,kh1); MFMA kh0 =====
        LOADF(a1, b1, L + 16384, L + 49152);
        if (t + 1 < NT) STAGE(t + 1, 1);
        __builtin_amdgcn_sched_barrier(0);
        __builtin_amdgcn_s_setprio(1);
        MMALL(a0, b0);
        __builtin_amdgcn_s_setprio(0);
        __builtin_amdgcn_sched_barrier(0);
        if (t + 1 < NT)                          // (t+1,kh0) landed; (t+1,kh1) stays
            asm volatile("s_waitcnt vmcnt(4)" ::: "memory");
        __builtin_amdgcn_s_barrier();

        // ===== P1: load (t+1,kh0) frags; stage (t+2,kh0); MFMA kh1 =====
        if (t + 1 < NT) LOADF(a0, b0, Ln + 0, Ln + 32768);
        if (t + 2 < NT) STAGE(t + 2, 0);
        __builtin_amdgcn_sched_barrier(0);
        __builtin_amdgcn_s_setprio(1);
        MMALL(a1, b1);
        __builtin_amdgcn_s_setprio(0);
        __builtin_amdgcn_sched_barrier(0);
        if (t + 2 < NT)                          // (t+1,kh1) landed; (t+2,kh0) stays
            asm volatile("s_waitcnt vmcnt(4)" ::: "memory");
        else if (t + 1 < NT)
            asm volatile("s_waitcnt vmcnt(0)" ::: "memory");
        __builtin_amdgcn_s_barrier();
    }

    // ---- epilogue: direct stores; D row=co, col=m; lanes 0-15 contiguous in w
    const int mwave = m0 + wm0;
    const int co0 = wn0 + (fg << 2);
    #pragma unroll
    for (int mf = 0; mf < 8; ++mf) {
        int m = mwave + mf * 16 + fr;
        int n = m / IMGHW;
        int hwr = m - n * IMGHW;
        uint32_t basem = (uint32_t)(n * (CO_ * IMGHW) + hwr);
        #pragma unroll
        for (int nf = 0; nf < 4; ++nf)
            #pragma unroll
            for (int q = 0; q < 4; ++q)
                out[basem + (uint32_t)(co0 + nf * 16 + q) * IMGHW] = acc[mf][nf][q];
    }
    #undef LOADF
    #undef MMALL
}

// ================= fallback (round-1 kernel, used if ws too small) ==========
#define BM    64
#define BK    32
#define NSTEP 36
#define LDSP  40

template<bool PACKED>
__global__ __launch_bounds__(256, 2)
void conv_fb(const float* __restrict__ x,
             const float* __restrict__ wraw,
             const unsigned short* __restrict__ wp,
             float* __restrict__ out)
{
    __shared__ __align__(16) unsigned short Al[2][BM][LDSP];
    __shared__ __align__(16) unsigned short Bl[2][CO_][LDSP];

    const int tid  = threadIdx.x;
    const int lane = tid & 63;
    const int wid  = tid >> 6;

    const int mb    = blockIdx.x;
    const int n_img = mb / 49;
    const int hw0   = (mb - n_img * 49) * BM;

    const int mm = lane;
    const int hw = hw0 + mm;
    const int h  = hw / HW_;
    const int w_ = hw - h * HW_;

    const int bco  = tid >> 2;
    const int bkkg = tid & 3;

    float   aPF[8];
    ushort8 bPF[4];

    auto loadA = [&](int step) {
        int khkw = step >> 2;
        int kh = khkw / 3, kw = khkw - (khkw / 3) * 3;
        int ci0 = (step & 3) * BK + wid * 8;
        int ih = h + kh - 1, iw = w_ + kw - 1;
        bool valid = ((unsigned)ih < (unsigned)HW_) && ((unsigned)iw < (unsigned)HW_);
        const float* px = x + (((size_t)(n_img * CIN + ci0) * HW_ + ih) * HW_ + iw);
        #pragma unroll
        for (int e = 0; e < 8; ++e)
            aPF[e] = valid ? px[e * IMGHW] : 0.f;
    };
    auto writeA = [&](int buf) {
        ushort8 v;
        #pragma unroll
        for (int e = 0; e < 8; ++e) v[e] = f2bf(aPF[e]);
        *(ushort8*)&Al[buf][mm][wid * 8] = v;
    };
    auto loadB = [&](int step) {
        if (PACKED) {
            int k0 = step * BK;
            #pragma unroll
            for (int r = 0; r < 4; ++r)
                bPF[r] = *(const ushort8*)&wp[(r * 64 + bco) * KSZ + k0 + bkkg * 8];
        } else {
            int khkw = step >> 2;
            int ci0 = (step & 3) * BK + bkkg * 8;
            #pragma unroll
            for (int r = 0; r < 4; ++r) {
                int co = r * 64 + bco;
                ushort8 v;
                #pragma unroll
                for (int e = 0; e < 8; ++e)
                    v[e] = f2bf(wraw[(co * CIN + ci0 + e) * 9 + khkw]);
                bPF[r] = v;
            }
        }
    };
    auto writeB = [&](int buf) {
        #pragma unroll
        for (int r = 0; r < 4; ++r)
            *(ushort8*)&Bl[buf][r * 64 + bco][bkkg * 8] = bPF[r];
    };

    f32x4 acc[4][4];
    #pragma unroll
    for (int i = 0; i < 4; ++i)
        #pragma unroll
        for (int j = 0; j < 4; ++j)
            acc[i][j] = (f32x4){0.f, 0.f, 0.f, 0.f};

    const int frow = lane & 15;
    const int fk   = (lane >> 4) * 8;

    loadA(0); loadB(0);
    writeA(0); writeB(0);
    __syncthreads();

    for (int s = 0; s < NSTEP; ++s) {
        const int cur = s & 1;
        if (s + 1 < NSTEP) { loadA(s + 1); loadB(s + 1); }

        ushort8 aF[4], bF[4];
        #pragma unroll
        for (int i = 0; i < 4; ++i)
            aF[i] = *(const ushort8*)&Bl[cur][wid * 64 + i * 16 + frow][fk];
        #pragma unroll
        for (int j = 0; j < 4; ++j)
            bF[j] = *(const ushort8*)&Al[cur][j * 16 + frow][fk];

        #pragma unroll
        for (int i = 0; i < 4; ++i)
            #pragma unroll
            for (int j = 0; j < 4; ++j)
                acc[i][j] = __builtin_amdgcn_mfma_f32_16x16x32_bf16(
                    __builtin_bit_cast(bf16x8, aF[i]),
                    __builtin_bit_cast(bf16x8, bF[j]),
                    acc[i][j], 0, 0, 0);

        if (s + 1 < NSTEP) { writeA(cur ^ 1); writeB(cur ^ 1); }
        __syncthreads();
    }

    float* ob = out + (size_t)n_img * (CO_ * IMGHW) + hw0;
    #pragma unroll
    for (int i = 0; i < 4; ++i) {
        int co0 = wid * 64 + i * 16 + (lane >> 4) * 4;
        #pragma unroll
        for (int j = 0; j < 4; ++j) {
            int mcol = j * 16 + (lane & 15);
            #pragma unroll
            for (int q = 0; q < 4; ++q)
                ob[(size_t)(co0 + q) * IMGHW + mcol] = acc[i][j][q];
        }
    }
}

extern "C" void kernel_launch(void* const* d_in, const int* in_sizes, int n_in,
                              void* d_out, int out_size, void* d_ws, size_t ws_size,
                              hipStream_t stream) {
    (void)in_sizes; (void)n_in; (void)out_size;
    const float* x  = (const float*)d_in[0];
    const float* wt = (const float*)d_in[1];
    float* out = (float*)d_out;

    if (ws_size >= WS_NEED) {
        unsigned short* xt  = (unsigned short*)d_ws;
        unsigned short* wpk = (unsigned short*)((char*)d_ws + XT_BYTES);
        xform<<<32 * HP, 256, 0, stream>>>(x, xt);
        pack_weight<<<(CO_ * KSZ) / 256, 256, 0, stream>>>(wt, wpk);
        convrd<<<392, 512, 0, stream>>>(xt, wpk, out);
    } else if (ws_size >= WP_BYTES) {
        unsigned short* wpk = (unsigned short*)d_ws;
        pack_weight<<<(CO_ * KSZ) / 256, 256, 0, stream>>>(wt, wpk);
        conv_fb<true><<<100352 / BM, 256, 0, stream>>>(x, wt, wpk, out);
    } else {
        conv_fb<false><<<100352 / BM, 256, 0, stream>>>(x, wt, nullptr, out);
    }
}

// Round 9
// 93.495 us; speedup vs baseline: 1.4104x; 1.0692x over previous
//
#include <hip/hip_runtime.h>
#include <stdint.h>

// Conv2d as implicit GEMM, bf16 MFMA.
// R9: 256x256 tile, BK=64, 4 phases/K-tile with ONE barrier per phase
// (cross-wave ds_read/MFMA overlap), uniform 2-load half-tile staging,
// counted vmcnt(2) gates at P0/P3 only (never drains mid-loop).
// GEMM: M=100352, N=256, K=1152 (k=(kh*3+kw)*128+ci). 18 K-tiles. Grid 392.

#define CIN   128
#define HW_   56
#define CO_   256
#define KSZ   1152
#define IMGHW 3136
#define HP    58
#define NT    18
#define BUFSZ 65536        // 4 planes x 16KB: A-lo A-hi B-lo B-hi
#define XT_BYTES ((size_t)32 * HP * HP * CIN * 2)   // 27,557,888
#define WP_BYTES ((size_t)CO_ * KSZ * 2)            // 589,824
#define WS_NEED  (XT_BYTES + WP_BYTES)

typedef __attribute__((ext_vector_type(8))) __bf16 bf16x8;
typedef __attribute__((ext_vector_type(4))) float f32x4;
typedef __attribute__((ext_vector_type(8))) unsigned short ushort8;

__device__ __forceinline__ unsigned short f2bf(float f) {
    unsigned int u = __float_as_uint(f);
    u += 0x7fffu + ((u >> 16) & 1u);   // RNE
    return (unsigned short)(u >> 16);
}

__device__ __forceinline__ void gl2lds16(const void* g, void* l) {
    __builtin_amdgcn_global_load_lds(
        (const __attribute__((address_space(1))) void*)g,
        (__attribute__((address_space(3))) void*)l, 16, 0, 0);
}

// ---- weight pack: [co][ci][kh][kw] f32 -> [co][k] bf16, k=(kh*3+kw)*128+ci
__global__ void pack_weight(const float* __restrict__ w,
                            unsigned short* __restrict__ wp) {
    int idx = blockIdx.x * 256 + threadIdx.x;
    int co = idx / KSZ;
    int k  = idx - co * KSZ;
    int khkw = k >> 7;
    int ci = k & 127;
    wp[idx] = f2bf(w[(co * CIN + ci) * 9 + khkw]);
}

// ---- x transform v2: NCHW f32 -> padded NHWC bf16 [32][58][58][128]
// float4 coalesced reads, ushort2 LDS transpose, dwordx4 stores.
__global__ __launch_bounds__(256)
void xform(const float* __restrict__ x, unsigned short* __restrict__ xt) {
    const int nb = blockIdx.x;
    const int n  = nb / HP;
    const int hp = nb - n * HP;
    unsigned short* orow = xt + ((size_t)n * HP + hp) * (HP * CIN);
    const int t = threadIdx.x;

    if (hp == 0 || hp == HP - 1) {
        for (int i = t; i < (HP * CIN) / 8; i += 256)
            ((ushort8*)orow)[i] = (ushort8){0, 0, 0, 0, 0, 0, 0, 0};
        return;
    }
    const int h = hp - 1;
    __shared__ ushort2 T[CIN][31];              // w-pairs 0..27 used, stride 31
    {
        const int ci = t >> 1, part = t & 1;
        const float* src = x + (((size_t)n * CIN + ci) * IMGHW + h * HW_ + part * 28);
        #pragma unroll
        for (int j = 0; j < 7; ++j) {
            float4 v = *(const float4*)(src + 4 * j);
            T[ci][part * 14 + 2 * j]     = (ushort2){f2bf(v.x), f2bf(v.y)};
            T[ci][part * 14 + 2 * j + 1] = (ushort2){f2bf(v.z), f2bf(v.w)};
        }
    }
    __syncthreads();
    const int wpg = t >> 4, cig = t & 15;       // wp-stride 16, 8 ci per thread
    const int ci0 = cig * 8;
    for (int wp_ = wpg; wp_ < HP; wp_ += 16) {
        ushort8 v = (ushort8){0, 0, 0, 0, 0, 0, 0, 0};
        const int w_ = wp_ - 1;
        if ((unsigned)w_ < (unsigned)HW_) {
            #pragma unroll
            for (int e = 0; e < 8; ++e) {
                ushort2 p = T[ci0 + e][w_ >> 1];
                v[e] = (w_ & 1) ? p.y : p.x;
            }
        }
        *(ushort8*)(orow + wp_ * CIN + ci0) = v;
    }
}

// ---- main conv: 256x256 tile, BK=64, 8 waves (2m x 4n), wave 128x64
__global__ __launch_bounds__(512, 2)
void conv1b(const unsigned short* __restrict__ xt,
            const unsigned short* __restrict__ wpk,
            float* __restrict__ out)
{
    __shared__ __align__(16) char lds[2 * BUFSZ];   // 128 KiB, 1 block/CU

    const int tid  = threadIdx.x;
    const int lane = tid & 63;
    const int wid  = tid >> 6;

    int bid = blockIdx.x;
    bid = (bid & 7) * 49 + (bid >> 3);          // XCD swizzle, 392 = 8*49 bijective
    const int m0 = bid << 8;

    // ---- staging: dest row = tid>>3 (+64 per 8KB sub-half), phys chunk tid&7
    // logical chunk (of the 8 x 16B in a 128B row) = (tid&7) ^ (row&7)
    const int lc = (tid & 7) ^ ((tid >> 3) & 7);
    uint32_t aoff[4], boff[4];
    #pragma unroll
    for (int q = 0; q < 4; ++q) {
        int m = m0 + q * 64 + (tid >> 3);
        int n = m / IMGHW;
        int rem = m - n * IMGHW;
        int h = rem / HW_;
        int w = rem - h * HW_;
        aoff[q] = (uint32_t)((((n * HP + h) * HP + w) << 8) + (lc << 4));
        boff[q] = (uint32_t)((q * 64 + (tid >> 3)) * (KSZ * 2) + (lc << 4));
    }

    // ---- fragment LDS offsets: phys chunk = (kh*4+fg) ^ (fr&7) ----
    const int fr = lane & 15, fg = lane >> 4;
    const int cK0 = ((fg ^ (fr & 7)) << 4);           // kh0 chunks 0..3
    const int cK1 = (((4 | fg) ^ (fr & 7)) << 4);     // kh1 chunks 4..7
    const int wm0 = (wid >> 2) << 7;            // 0 / 128
    const int wn0 = (wid & 3) << 6;             // 0..192
    const int APB = (wid >> 2) ? 16384 : 0;                 // wave's A plane
    const int BPB = 32768 + ((wid & 2) ? 16384 : 0);        // wave's B plane
    const int aBase = APB + fr * 128;                       // + mf*2048 + cK
    const int bBase = BPB + ((wid & 1) * 64 + fr) * 128;    // + nf*2048 + cK

    const char* xtc = (const char*)xt;
    const char* wpc = (const char*)wpk;

    f32x4 acc[8][4];
    #pragma unroll
    for (int i = 0; i < 8; ++i)
        #pragma unroll
        for (int j = 0; j < 4; ++j)
            acc[i][j] = (f32x4){0.f, 0.f, 0.f, 0.f};

    ushort8 areg[4], breg[4];

    // stage pair 'sp' of tile tt (2 gl2lds): sp0:{Alo.p0,Ahi.p0} sp1:{Blo.p0,Blo.p1}
    // sp2:{Bhi.p0,Bhi.p1} sp3:{Alo.p1,Ahi.p1}
    auto STAGE = [&](int tt, int sp) {
        const int bo = (tt & 1) << 16;
        int tap = tt >> 1;
        int khr = (tap * 11) >> 5;              // tap/3 for tap<9
        int kwr = tap - khr * 3;
        uint32_t asl = (uint32_t)(((khr * HP + kwr) << 8) + ((tt & 1) << 7));
        uint32_t bsl = (uint32_t)(tt << 7);
        char* L = &lds[bo];
        switch (sp) {
        case 0:
            gl2lds16(xtc + aoff[0] + asl, L + 0     + tid * 16);
            gl2lds16(xtc + aoff[2] + asl, L + 16384 + tid * 16);
            break;
        case 1:
            gl2lds16(wpc + boff[0] + bsl, L + 32768 + tid * 16);
            gl2lds16(wpc + boff[1] + bsl, L + 40960 + tid * 16);
            break;
        case 2:
            gl2lds16(wpc + boff[2] + bsl, L + 49152 + tid * 16);
            gl2lds16(wpc + boff[3] + bsl, L + 57344 + tid * 16);
            break;
        default:
            gl2lds16(xtc + aoff[1] + asl, L + 8192  + tid * 16);
            gl2lds16(xtc + aoff[3] + asl, L + 24576 + tid * 16);
            break;
        }
    };

    #define SBAR0 __builtin_amdgcn_sched_barrier(0)
    #define MM16(mbase) do { \
        _Pragma("unroll") for (int mf_ = 0; mf_ < 4; ++mf_) \
            _Pragma("unroll") for (int nf_ = 0; nf_ < 4; ++nf_) \
                acc[(mbase) + mf_][nf_] = __builtin_amdgcn_mfma_f32_16x16x32_bf16( \
                    __builtin_bit_cast(bf16x8, breg[nf_]), \
                    __builtin_bit_cast(bf16x8, areg[mf_]), \
                    acc[(mbase) + mf_][nf_], 0, 0, 0); \
    } while (0)

    // ---- prologue: tile0's four stage-pairs; first 3 pairs (6 loads) landed
    STAGE(0, 0); STAGE(0, 1); STAGE(0, 2); STAGE(0, 3);
    asm volatile("s_waitcnt vmcnt(2)" ::: "memory");
    __builtin_amdgcn_s_barrier();

    #pragma unroll 1
    for (int t = 0; t < NT; ++t) {
        const int bo = (t & 1) << 16;
        const char* L = lds + bo;
        const bool pf = (t + 1 < NT);

        // ===== P0: frags (mf0-3 + b, kh0); stage sp0(t+1); gate A.p1(t) =====
        #pragma unroll
        for (int nf = 0; nf < 4; ++nf)
            breg[nf] = *(const ushort8*)(L + bBase + nf * 2048 + cK0);
        #pragma unroll
        for (int mf = 0; mf < 4; ++mf)
            areg[mf] = *(const ushort8*)(L + aBase + mf * 2048 + cK0);
        if (pf) STAGE(t + 1, 0);
        SBAR0;
        if (pf) asm volatile("s_waitcnt vmcnt(2)" ::: "memory");
        else    asm volatile("s_waitcnt vmcnt(0)" ::: "memory");
        __builtin_amdgcn_s_barrier();
        asm volatile("s_waitcnt lgkmcnt(0)" ::: "memory");
        SBAR0;
        __builtin_amdgcn_s_setprio(1);
        MM16(0);
        __builtin_amdgcn_s_setprio(0);

        // ===== P1: frags (mf4-7, kh0; b reused); stage sp1(t+1) =====
        #pragma unroll
        for (int mf = 0; mf < 4; ++mf)
            areg[mf] = *(const ushort8*)(L + aBase + (mf + 4) * 2048 + cK0);
        if (pf) STAGE(t + 1, 1);
        SBAR0;
        __builtin_amdgcn_s_barrier();
        asm volatile("s_waitcnt lgkmcnt(0)" ::: "memory");
        SBAR0;
        __builtin_amdgcn_s_setprio(1);
        MM16(4);
        __builtin_amdgcn_s_setprio(0);

        // ===== P2: frags (mf0-3 + b, kh1); stage sp2(t+1) =====
        #pragma unroll
        for (int nf = 0; nf < 4; ++nf)
            breg[nf] = *(const ushort8*)(L + bBase + nf * 2048 + cK1);
        #pragma unroll
        for (int mf = 0; mf < 4; ++mf)
            areg[mf] = *(const ushort8*)(L + aBase + mf * 2048 + cK1);
        if (pf) STAGE(t + 1, 2);
        SBAR0;
        __builtin_amdgcn_s_barrier();
        asm volatile("s_waitcnt lgkmcnt(0)" ::: "memory");
        SBAR0;
        __builtin_amdgcn_s_setprio(1);
        MM16(0);
        __builtin_amdgcn_s_setprio(0);

        // ===== P3: frags (mf4-7, kh1); stage sp3(t+1); gate next tile's 6 =====
        #pragma unroll
        for (int mf = 0; mf < 4; ++mf)
            areg[mf] = *(const ushort8*)(L + aBase + (mf + 4) * 2048 + cK1);
        if (pf) STAGE(t + 1, 3);
        SBAR0;
        if (pf) asm volatile("s_waitcnt vmcnt(2)" ::: "memory");
        __builtin_amdgcn_s_barrier();
        asm volatile("s_waitcnt lgkmcnt(0)" ::: "memory");
        SBAR0;
        __builtin_amdgcn_s_setprio(1);
        MM16(4);
        __builtin_amdgcn_s_setprio(0);
    }

    // ---- epilogue: direct stores; D row=co, col=m; lanes 0-15 contiguous in w
    const int mwave = m0 + wm0;
    const int co0 = wn0 + (fg << 2);
    #pragma unroll
    for (int mf = 0; mf < 8; ++mf) {
        int m = mwave + mf * 16 + fr;
        int n = m / IMGHW;
        int hwr = m - n * IMGHW;
        uint32_t basem = (uint32_t)(n * (CO_ * IMGHW) + hwr);
        #pragma unroll
        for (int nf = 0; nf < 4; ++nf)
            #pragma unroll
            for (int q = 0; q < 4; ++q)
                out[basem + (uint32_t)(co0 + nf * 16 + q) * IMGHW] = acc[mf][nf][q];
    }
    #undef SBAR0
    #undef MM16
}

// ================= fallback (round-1 kernel, used if ws too small) ==========
#define BM    64
#define BK    32
#define NSTEP 36
#define LDSP  40

template<bool PACKED>
__global__ __launch_bounds__(256, 2)
void conv_fb(const float* __restrict__ x,
             const float* __restrict__ wraw,
             const unsigned short* __restrict__ wp,
             float* __restrict__ out)
{
    __shared__ __align__(16) unsigned short Al[2][BM][LDSP];
    __shared__ __align__(16) unsigned short Bl[2][CO_][LDSP];

    const int tid  = threadIdx.x;
    const int lane = tid & 63;
    const int wid  = tid >> 6;

    const int mb    = blockIdx.x;
    const int n_img = mb / 49;
    const int hw0   = (mb - n_img * 49) * BM;

    const int mm = lane;
    const int hw = hw0 + mm;
    const int h  = hw / HW_;
    const int w_ = hw - h * HW_;

    const int bco  = tid >> 2;
    const int bkkg = tid & 3;

    float   aPF[8];
    ushort8 bPF[4];

    auto loadA = [&](int step) {
        int khkw = step >> 2;
        int kh = khkw / 3, kw = khkw - (khkw / 3) * 3;
        int ci0 = (step & 3) * BK + wid * 8;
        int ih = h + kh - 1, iw = w_ + kw - 1;
        bool valid = ((unsigned)ih < (unsigned)HW_) && ((unsigned)iw < (unsigned)HW_);
        const float* px = x + (((size_t)(n_img * CIN + ci0) * HW_ + ih) * HW_ + iw);
        #pragma unroll
        for (int e = 0; e < 8; ++e)
            aPF[e] = valid ? px[e * IMGHW] : 0.f;
    };
    auto writeA = [&](int buf) {
        ushort8 v;
        #pragma unroll
        for (int e = 0; e < 8; ++e) v[e] = f2bf(aPF[e]);
        *(ushort8*)&Al[buf][mm][wid * 8] = v;
    };
    auto loadB = [&](int step) {
        if (PACKED) {
            int k0 = step * BK;
            #pragma unroll
            for (int r = 0; r < 4; ++r)
                bPF[r] = *(const ushort8*)&wp[(r * 64 + bco) * KSZ + k0 + bkkg * 8];
        } else {
            int khkw = step >> 2;
            int ci0 = (step & 3) * BK + bkkg * 8;
            #pragma unroll
            for (int r = 0; r < 4; ++r) {
                int co = r * 64 + bco;
                ushort8 v;
                #pragma unroll
                for (int e = 0; e < 8; ++e)
                    v[e] = f2bf(wraw[(co * CIN + ci0 + e) * 9 + khkw]);
                bPF[r] = v;
            }
        }
    };
    auto writeB = [&](int buf) {
        #pragma unroll
        for (int r = 0; r < 4; ++r)
            *(ushort8*)&Bl[buf][r * 64 + bco][bkkg * 8] = bPF[r];
    };

    f32x4 acc[4][4];
    #pragma unroll
    for (int i = 0; i < 4; ++i)
        #pragma unroll
        for (int j = 0; j < 4; ++j)
            acc[i][j] = (f32x4){0.f, 0.f, 0.f, 0.f};

    const int frow = lane & 15;
    const int fk   = (lane >> 4) * 8;

    loadA(0); loadB(0);
    writeA(0); writeB(0);
    __syncthreads();

    for (int s = 0; s < NSTEP; ++s) {
        const int cur = s & 1;
        if (s + 1 < NSTEP) { loadA(s + 1); loadB(s + 1); }

        ushort8 aF[4], bF[4];
        #pragma unroll
        for (int i = 0; i < 4; ++i)
            aF[i] = *(const ushort8*)&Bl[cur][wid * 64 + i * 16 + frow][fk];
        #pragma unroll
        for (int j = 0; j < 4; ++j)
            bF[j] = *(const ushort8*)&Al[cur][j * 16 + frow][fk];

        #pragma unroll
        for (int i = 0; i < 4; ++i)
            #pragma unroll
            for (int j = 0; j < 4; ++j)
                acc[i][j] = __builtin_amdgcn_mfma_f32_16x16x32_bf16(
                    __builtin_bit_cast(bf16x8, aF[i]),
                    __builtin_bit_cast(bf16x8, bF[j]),
                    acc[i][j], 0, 0, 0);

        if (s + 1 < NSTEP) { writeA(cur ^ 1); writeB(cur ^ 1); }
        __syncthreads();
    }

    float* ob = out + (size_t)n_img * (CO_ * IMGHW) + hw0;
    #pragma unroll
    for (int i = 0; i < 4; ++i) {
        int co0 = wid * 64 + i * 16 + (lane >> 4) * 4;
        #pragma unroll
        for (int j = 0; j < 4; ++j) {
            int mcol = j * 16 + (lane & 15);
            #pragma unroll
            for (int q = 0; q < 4; ++q)
                ob[(size_t)(co0 + q) * IMGHW + mcol] = acc[i][j][q];
        }
    }
}

extern "C" void kernel_launch(void* const* d_in, const int* in_sizes, int n_in,
                              void* d_out, int out_size, void* d_ws, size_t ws_size,
                              hipStream_t stream) {
    (void)in_sizes; (void)n_in; (void)out_size;
    const float* x  = (const float*)d_in[0];
    const float* wt = (const float*)d_in[1];
    float* out = (float*)d_out;

    if (ws_size >= WS_NEED) {
        unsigned short* xt  = (unsigned short*)d_ws;
        unsigned short* wpk = (unsigned short*)((char*)d_ws + XT_BYTES);
        xform<<<32 * HP, 256, 0, stream>>>(x, xt);
        pack_weight<<<(CO_ * KSZ) / 256, 256, 0, stream>>>(wt, wpk);
        conv1b<<<392, 512, 0, stream>>>(xt, wpk, out);
    } else if (ws_size >= WP_BYTES) {
        unsigned short* wpk = (unsigned short*)d_ws;
        pack_weight<<<(CO_ * KSZ) / 256, 256, 0, stream>>>(wt, wpk);
        conv_fb<true><<<100352 / BM, 256, 0, stream>>>(x, wt, wpk, out);
    } else {
        conv_fb<false><<<100352 / BM, 256, 0, stream>>>(x, wt, nullptr, out);
    }
}